// Round 1
// baseline (601.991 us; speedup 1.0000x reference)
//
#include <hip/hip_runtime.h>

// Locally connected layer, fp32.
// out[n,o,l] = sum_k x_unf[n,l,k] * w[o,l,k] + bias[o,l]
//   l = ho*62 + wo,  k = c*9 + i*3 + j,  x_unf[n,l,k] = x[n,c,ho+i,wo+j]
// One block per l: 64x64x288 GEMM, 256 threads, 4x4 register tile.
// K staged in 9 chunks of 32 into k-major LDS (row stride 68 floats for
// 16B-aligned float4 compute reads).

#define L_TOT 3844
#define K_TOT 288
#define LDS_STRIDE 68  // 32-k rows, 64 (+4 pad) entries; 68*4B keeps rows 16B-aligned

__global__ __launch_bounds__(256, 4)
void lc_fp32_kernel(const float* __restrict__ x,
                    const float* __restrict__ w,
                    const float* __restrict__ b,
                    float* __restrict__ out) {
    __shared__ float Xs[32][LDS_STRIDE];
    __shared__ float Ws[32][LDS_STRIDE];
    __shared__ int offs[K_TOT];

    const int tid = threadIdx.x;

    // per-k offset into x: c*H*W + i*W + j  (H=W=64)
    for (int k = tid; k < K_TOT; k += 256) {
        int c = k / 9, rem = k % 9;
        offs[k] = c * 4096 + (rem / 3) * 64 + (rem % 3);
    }

    // Bijective XCD swizzle (nwg=3844 = 8*480+4): consecutive l on one XCD
    // so neighboring blocks' 4B out-stores write-combine in that XCD's L2.
    const int orig = blockIdx.x;
    const int xcd = orig & 7;
    const int slot = orig >> 3;
    const int l = (xcd < 4) ? (xcd * 481 + slot)
                            : (1924 + (xcd - 4) * 480 + slot);

    const int ho = l / 62, wo = l % 62;
    const int xbase = ho * 64 + wo;

    const int tx = tid & 15;   // o tile index (4 o's per thread)
    const int ty = tid >> 4;   // n tile index (4 n's per thread)

    float acc[4][4] = {{0.f}};

    __syncthreads();  // offs ready; also guards first-iteration LDS writes

    for (int kk = 0; kk < K_TOT; kk += 32) {
        // Stage X chunk: element (n = idx>>5, k = idx&31) -> Xs[k][n].
        // Lanes walk k (gather-ish in x, but x is L2/L3-resident).
        #pragma unroll
        for (int p = 0; p < 8; ++p) {
            int idx = (p << 8) + tid;
            int n = idx >> 5, k = idx & 31;
            Xs[k][n] = x[n * 131072 + xbase + offs[kk + k]];
        }
        // Stage W chunk: element (o = idx>>5, k = idx&31) -> Ws[k][o].
        // Lanes walk k -> 128B contiguous per o row: coalesced (the 283MB stream).
        #pragma unroll
        for (int p = 0; p < 8; ++p) {
            int idx = (p << 8) + tid;
            int o = idx >> 5, k = idx & 31;
            Ws[k][o] = w[(o * L_TOT + l) * K_TOT + kk + k];
        }
        __syncthreads();

        #pragma unroll
        for (int k = 0; k < 32; ++k) {
            const float4 av = *(const float4*)(&Xs[k][ty * 4]);  // 16-lane broadcast
            const float4 bv = *(const float4*)(&Ws[k][tx * 4]);
            const float am[4] = {av.x, av.y, av.z, av.w};
            const float bm[4] = {bv.x, bv.y, bv.z, bv.w};
            #pragma unroll
            for (int m = 0; m < 4; ++m)
                #pragma unroll
                for (int j = 0; j < 4; ++j)
                    acc[m][j] = fmaf(am[m], bm[j], acc[m][j]);
        }
        __syncthreads();
    }

    // Epilogue: + bias, scattered 4B stores (stride 3844 floats between o's).
    float bv[4];
    #pragma unroll
    for (int j = 0; j < 4; ++j) bv[j] = b[(tx * 4 + j) * L_TOT + l];

    #pragma unroll
    for (int m = 0; m < 4; ++m) {
        const int n = ty * 4 + m;
        #pragma unroll
        for (int j = 0; j < 4; ++j) {
            const int o = tx * 4 + j;
            out[(n * 64 + o) * L_TOT + l] = acc[m][j] + bv[j];
        }
    }
}

extern "C" void kernel_launch(void* const* d_in, const int* in_sizes, int n_in,
                              void* d_out, int out_size, void* d_ws, size_t ws_size,
                              hipStream_t stream) {
    const float* x = (const float*)d_in[0];   // (64,32,64,64) fp32
    const float* w = (const float*)d_in[1];   // (64,3844,288) fp32
    const float* b = (const float*)d_in[2];   // (64,3844) fp32
    float* out = (float*)d_out;               // (64,64,62,62) fp32

    hipLaunchKernelGGL(lc_fp32_kernel, dim3(L_TOT), dim3(256), 0, stream,
                       x, w, b, out);
}